// Round 2
// baseline (175.563 us; speedup 1.0000x reference)
//
#include <hip/hip_runtime.h>
#include <hip/hip_bf16.h>

// Problem constants
#define NB    4096          // batch
#define ND    256           // dim
#define NP    2             // positives per anchor
#define TOT   (NB * 3)      // 12288 rows: [a | p0 | p1]
#define NCHUNK 32
#define COLS_PER_CHUNK (TOT / NCHUNK)          // 384
#define TILES_PER_CHUNK (COLS_PER_CHUNK / 16)  // 24
#define NEG_INIT (-4.0f)

typedef __bf16 bf16x8 __attribute__((ext_vector_type(8)));
typedef float  f32x4  __attribute__((ext_vector_type(4)));

// ws layout (bytes)
#define WS_F_OFF    0                            // ushort[12288*256] bf16 normalized
#define WS_POS_OFF  (TOT * ND * 2)               // float[4096*2] pos distances
#define WS_PART_OFF (WS_POS_OFF + NB * NP * 4)   // float[4096][NCHUNK][3] partial maxima

__device__ __forceinline__ unsigned short f2bf(float f) {
    unsigned u = __float_as_uint(f);
    u += 0x7fffu + ((u >> 16) & 1u);   // round-to-nearest-even
    return (unsigned short)(u >> 16);
}

// Kernel 1: normalize rows of [a | p0 | p1] -> bf16 matrix F, and for p-rows
// also compute the exact fp32 positive distance (normalized dot with anchor).
// One wave per row; lane handles 4 consecutive floats.
__global__ void norm_pos_kernel(const float* __restrict__ anchor,
                                const float* __restrict__ positive,
                                unsigned short* __restrict__ F,
                                float* __restrict__ posArr) {
    int wid = threadIdx.x >> 6, lane = threadIdx.x & 63;
    int row = blockIdx.x * 4 + wid;              // grid = 3072
    if (row < NB) {
        const float* src = anchor + (size_t)row * ND;
        float4 x = *(const float4*)(src + lane * 4);
        float ss = x.x * x.x + x.y * x.y + x.z * x.z + x.w * x.w;
        #pragma unroll
        for (int m = 1; m < 64; m <<= 1) ss += __shfl_xor(ss, m, 64);
        float inv = 1.0f / fmaxf(sqrtf(ss), 1e-12f);
        ushort4 o;
        o.x = f2bf(x.x * inv); o.y = f2bf(x.y * inv);
        o.z = f2bf(x.z * inv); o.w = f2bf(x.w * inv);
        *(ushort4*)(F + (size_t)row * ND + lane * 4) = o;
    } else {
        int q = row - NB;
        int v = q >> 12;                         // 0 or 1
        int j = q & (NB - 1);
        const float* sp = positive + (size_t)(j * NP + v) * ND;
        const float* sa = anchor + (size_t)j * ND;
        float4 xp = *(const float4*)(sp + lane * 4);
        float4 xa = *(const float4*)(sa + lane * 4);
        float sspv = xp.x * xp.x + xp.y * xp.y + xp.z * xp.z + xp.w * xp.w;
        float ssa  = xa.x * xa.x + xa.y * xa.y + xa.z * xa.z + xa.w * xa.w;
        float dot  = xa.x * xp.x + xa.y * xp.y + xa.z * xp.z + xa.w * xp.w;
        #pragma unroll
        for (int m = 1; m < 64; m <<= 1) {
            sspv += __shfl_xor(sspv, m, 64);
            ssa  += __shfl_xor(ssa, m, 64);
            dot  += __shfl_xor(dot, m, 64);
        }
        float invp = 1.0f / fmaxf(sqrtf(sspv), 1e-12f);
        ushort4 o;
        o.x = f2bf(xp.x * invp); o.y = f2bf(xp.y * invp);
        o.z = f2bf(xp.z * invp); o.w = f2bf(xp.w * invp);
        *(ushort4*)(F + (size_t)row * ND + lane * 4) = o;
        if (lane == 0) {
            float inva = 1.0f / fmaxf(sqrtf(ssa), 1e-12f);
            float dn = dot * inva * invp;
            float sq = 2.0f - 2.0f * dn;
            posArr[j * NP + v] = sqrtf(fmaxf(sq, 1e-12f));
        }
    }
}

// Kernel 2: fused masked-max Gram. Each wave: 32 anchor rows (2 x 16-row MFMA
// sets, A frags register-resident) x 384-column chunk. Running per-part max.
__global__ __launch_bounds__(256) void gram_max_kernel(
        const unsigned short* __restrict__ F,
        const int* __restrict__ labels,
        float* __restrict__ partials) {
    int wid = threadIdx.x >> 6, lane = threadIdx.x & 63;
    int l15 = lane & 15, quad = lane >> 4;
    int rowBase = blockIdx.x * 128 + wid * 32;   // gridDim.x = 32
    int chunk = blockIdx.y;                      // gridDim.y = NCHUNK

    // Preload A fragments: af[s][kk] covers rows rowBase+s*16.. , K = kk*32
    bf16x8 af[2][8];
    #pragma unroll
    for (int s = 0; s < 2; ++s) {
        const unsigned short* ar = F + (size_t)(rowBase + s * 16 + l15) * ND + quad * 8;
        #pragma unroll
        for (int kk = 0; kk < 8; ++kk)
            af[s][kk] = *(const bf16x8*)(ar + kk * 32);
    }
    // Row labels for this lane's 8 C rows (C layout: row = quad*4 + reg)
    int rl[2][4];
    #pragma unroll
    for (int s = 0; s < 2; ++s)
        #pragma unroll
        for (int r = 0; r < 4; ++r)
            rl[s][r] = labels[rowBase + s * 16 + quad * 4 + r];

    float vmax0[2][4], vmax1[2][4], vmax2[2][4];
    #pragma unroll
    for (int s = 0; s < 2; ++s)
        #pragma unroll
        for (int r = 0; r < 4; ++r) {
            vmax0[s][r] = NEG_INIT; vmax1[s][r] = NEG_INIT; vmax2[s][r] = NEG_INIT;
        }

    for (int ct = 0; ct < TILES_PER_CHUNK; ++ct) {
        int colBase = chunk * COLS_PER_CHUNK + ct * 16;
        int part = colBase >> 12;                // wave-uniform: 0=aa, 1=p0, 2=p1
        int c = colBase + l15;
        int lc = labels[c & (NB - 1)];           // column label (shared mod NB)
        const unsigned short* br = F + (size_t)c * ND + quad * 8;
        bf16x8 bf[8];
        #pragma unroll
        for (int kk = 0; kk < 8; ++kk)
            bf[kk] = *(const bf16x8*)(br + kk * 32);

        // 4 independent MFMA chains of depth 4 (better dependent-latency hiding)
        f32x4 acc0a = {0.f,0.f,0.f,0.f}, acc0b = {0.f,0.f,0.f,0.f};
        f32x4 acc1a = {0.f,0.f,0.f,0.f}, acc1b = {0.f,0.f,0.f,0.f};
        #pragma unroll
        for (int kk = 0; kk < 4; ++kk) {
            acc0a = __builtin_amdgcn_mfma_f32_16x16x32_bf16(af[0][kk], bf[kk], acc0a, 0, 0, 0);
            acc0b = __builtin_amdgcn_mfma_f32_16x16x32_bf16(af[0][kk+4], bf[kk+4], acc0b, 0, 0, 0);
            acc1a = __builtin_amdgcn_mfma_f32_16x16x32_bf16(af[1][kk], bf[kk], acc1a, 0, 0, 0);
            acc1b = __builtin_amdgcn_mfma_f32_16x16x32_bf16(af[1][kk+4], bf[kk+4], acc1b, 0, 0, 0);
        }

        if (part == 0) {
            #pragma unroll
            for (int r = 0; r < 4; ++r) {
                float d0 = acc0a[r] + acc0b[r], d1 = acc1a[r] + acc1b[r];
                float c0 = (lc != rl[0][r]) ? d0 : NEG_INIT;
                float c1 = (lc != rl[1][r]) ? d1 : NEG_INIT;
                vmax0[0][r] = fmaxf(vmax0[0][r], c0);
                vmax0[1][r] = fmaxf(vmax0[1][r], c1);
            }
        } else if (part == 1) {
            #pragma unroll
            for (int r = 0; r < 4; ++r) {
                float d0 = acc0a[r] + acc0b[r], d1 = acc1a[r] + acc1b[r];
                float c0 = (lc != rl[0][r]) ? d0 : NEG_INIT;
                float c1 = (lc != rl[1][r]) ? d1 : NEG_INIT;
                vmax1[0][r] = fmaxf(vmax1[0][r], c0);
                vmax1[1][r] = fmaxf(vmax1[1][r], c1);
            }
        } else {
            #pragma unroll
            for (int r = 0; r < 4; ++r) {
                float d0 = acc0a[r] + acc0b[r], d1 = acc1a[r] + acc1b[r];
                float c0 = (lc != rl[0][r]) ? d0 : NEG_INIT;
                float c1 = (lc != rl[1][r]) ? d1 : NEG_INIT;
                vmax2[0][r] = fmaxf(vmax2[0][r], c0);
                vmax2[1][r] = fmaxf(vmax2[1][r], c1);
            }
        }
    }

    // Reduce max across the 16 column-lanes (same quad = same rows)
    #pragma unroll
    for (int m = 1; m < 16; m <<= 1) {
        #pragma unroll
        for (int s = 0; s < 2; ++s)
            #pragma unroll
            for (int r = 0; r < 4; ++r) {
                vmax0[s][r] = fmaxf(vmax0[s][r], __shfl_xor(vmax0[s][r], m, 64));
                vmax1[s][r] = fmaxf(vmax1[s][r], __shfl_xor(vmax1[s][r], m, 64));
                vmax2[s][r] = fmaxf(vmax2[s][r], __shfl_xor(vmax2[s][r], m, 64));
            }
    }
    if (l15 == 0) {
        #pragma unroll
        for (int s = 0; s < 2; ++s)
            #pragma unroll
            for (int r = 0; r < 4; ++r) {
                int row = rowBase + s * 16 + quad * 4 + r;
                float* o = partials + (size_t)row * (NCHUNK * 3) + chunk * 3;
                o[0] = vmax0[s][r];
                o[1] = vmax1[s][r];
                o[2] = vmax2[s][r];
            }
    }
}

// Kernel 3: combine chunk partials -> neg distances -> hinge loss -> mean.
// partials are [row][NCHUNK][3] -> each thread streams 384 contiguous bytes.
__global__ void finalize_kernel(const float* __restrict__ partials,
                                const float* __restrict__ posArr,
                                float* __restrict__ out) {
    int row = blockIdx.x * 256 + threadIdx.x;    // grid = 16 -> 4096 rows
    const float* pp = partials + (size_t)row * (NCHUNK * 3);
    float ma = NEG_INIT, m0 = NEG_INIT, m1 = NEG_INIT;
    #pragma unroll 8
    for (int c = 0; c < NCHUNK; ++c) {
        ma = fmaxf(ma, pp[c * 3 + 0]);
        m0 = fmaxf(m0, pp[c * 3 + 1]);
        m1 = fmaxf(m1, pp[c * 3 + 2]);
    }
    float n0 = sqrtf(fmaxf(2.0f - 2.0f * fmaxf(ma, m0), 1e-12f));
    float n1 = sqrtf(fmaxf(2.0f - 2.0f * fmaxf(ma, m1), 1e-12f));
    float l = fmaxf(posArr[row * 2 + 0] - n0 + 1.0f, 0.0f)
            + fmaxf(posArr[row * 2 + 1] - n1 + 1.0f, 0.0f);
    // block sum
    int lane = threadIdx.x & 63, wid = threadIdx.x >> 6;
    #pragma unroll
    for (int m = 1; m < 64; m <<= 1) l += __shfl_xor(l, m, 64);
    __shared__ float wsum[4];
    if (lane == 0) wsum[wid] = l;
    __syncthreads();
    if (threadIdx.x == 0) {
        float s = wsum[0] + wsum[1] + wsum[2] + wsum[3];
        atomicAdd(out, s * (1.0f / (NB * NP)));
    }
}

extern "C" void kernel_launch(void* const* d_in, const int* in_sizes, int n_in,
                              void* d_out, int out_size, void* d_ws, size_t ws_size,
                              hipStream_t stream) {
    const float* anchor   = (const float*)d_in[0];
    const float* positive = (const float*)d_in[1];
    const int*   labels   = (const int*)d_in[2];
    float* out = (float*)d_out;

    unsigned short* F = (unsigned short*)((char*)d_ws + WS_F_OFF);
    float* posArr     = (float*)((char*)d_ws + WS_POS_OFF);
    float* partials   = (float*)((char*)d_ws + WS_PART_OFF);

    norm_pos_kernel<<<TOT / 4, 256, 0, stream>>>(anchor, positive, F, posArr);
    gram_max_kernel<<<dim3(NB / 128, NCHUNK), 256, 0, stream>>>(F, labels, partials);
    hipMemsetAsync(d_out, 0, sizeof(float), stream);
    finalize_kernel<<<NB / 256, 256, 0, stream>>>(partials, posArr, out);
}

// Round 3
// 102.739 us; speedup vs baseline: 1.7088x; 1.7088x over previous
//
#include <hip/hip_runtime.h>
#include <hip/hip_bf16.h>

// Problem constants
#define NB    4096          // batch
#define ND    256           // dim
#define NP    2             // positives per anchor
#define TOT   (NB * 3)      // 12288 rows: [a | p0 | p1]
#define NCHUNK 24           // 3 parts x 8 chunks; each chunk = one Gram part slice
#define COLS_PER_CHUNK (TOT / NCHUNK)          // 512 (entirely within one part)
#define TILES (COLS_PER_CHUNK / 16)            // 32
#define PITCH 528                               // 512B row + 16B pad -> 2-way banks (free)
#define NEG_INIT (-4.0f)

typedef __bf16 bf16x8 __attribute__((ext_vector_type(8)));
typedef float  f32x4  __attribute__((ext_vector_type(4)));

// ws layout (bytes)
#define WS_F_OFF    0                            // ushort[12288*256] bf16 normalized
#define WS_POS_OFF  (TOT * ND * 2)               // float[4096*2] pos distances
#define WS_PART_OFF (WS_POS_OFF + NB * NP * 4)   // float[3][4096][8] partial maxima

__device__ __forceinline__ unsigned short f2bf(float f) {
    unsigned u = __float_as_uint(f);
    u += 0x7fffu + ((u >> 16) & 1u);   // round-to-nearest-even
    return (unsigned short)(u >> 16);
}

// Kernel 1: normalize rows of [a | p0 | p1] -> bf16 matrix F; p-rows also emit
// the exact fp32 positive distance. One wave per row.
__global__ void norm_pos_kernel(const float* __restrict__ anchor,
                                const float* __restrict__ positive,
                                unsigned short* __restrict__ F,
                                float* __restrict__ posArr) {
    int wid = threadIdx.x >> 6, lane = threadIdx.x & 63;
    int row = blockIdx.x * 4 + wid;              // grid = 3072
    if (row < NB) {
        const float* src = anchor + (size_t)row * ND;
        float4 x = *(const float4*)(src + lane * 4);
        float ss = x.x * x.x + x.y * x.y + x.z * x.z + x.w * x.w;
        #pragma unroll
        for (int m = 1; m < 64; m <<= 1) ss += __shfl_xor(ss, m, 64);
        float inv = 1.0f / fmaxf(sqrtf(ss), 1e-12f);
        ushort4 o;
        o.x = f2bf(x.x * inv); o.y = f2bf(x.y * inv);
        o.z = f2bf(x.z * inv); o.w = f2bf(x.w * inv);
        *(ushort4*)(F + (size_t)row * ND + lane * 4) = o;
    } else {
        int q = row - NB;
        int v = q >> 12;                         // 0 or 1
        int j = q & (NB - 1);
        const float* sp = positive + (size_t)(j * NP + v) * ND;
        const float* sa = anchor + (size_t)j * ND;
        float4 xp = *(const float4*)(sp + lane * 4);
        float4 xa = *(const float4*)(sa + lane * 4);
        float sspv = xp.x * xp.x + xp.y * xp.y + xp.z * xp.z + xp.w * xp.w;
        float ssa  = xa.x * xa.x + xa.y * xa.y + xa.z * xa.z + xa.w * xa.w;
        float dot  = xa.x * xp.x + xa.y * xp.y + xa.z * xp.z + xa.w * xp.w;
        #pragma unroll
        for (int m = 1; m < 64; m <<= 1) {
            sspv += __shfl_xor(sspv, m, 64);
            ssa  += __shfl_xor(ssa, m, 64);
            dot  += __shfl_xor(dot, m, 64);
        }
        float invp = 1.0f / fmaxf(sqrtf(sspv), 1e-12f);
        ushort4 o;
        o.x = f2bf(xp.x * invp); o.y = f2bf(xp.y * invp);
        o.z = f2bf(xp.z * invp); o.w = f2bf(xp.w * invp);
        *(ushort4*)(F + (size_t)row * ND + lane * 4) = o;
        if (lane == 0) {
            float inva = 1.0f / fmaxf(sqrtf(ssa), 1e-12f);
            float dn = dot * inva * invp;
            float sq = 2.0f - 2.0f * dn;
            posArr[j * NP + v] = sqrtf(fmaxf(sq, 1e-12f));
        }
    }
}

// Kernel 2: fused masked-max Gram with LDS-staged, double-buffered B tiles.
// Block = 4 waves x 32 rows = 128 rows; all waves share each 16-col B tile.
__global__ __launch_bounds__(256) void gram_max_kernel(
        const unsigned short* __restrict__ F,
        const int* __restrict__ labels,
        float* __restrict__ partials) {
    __shared__ unsigned char lds[2][16 * PITCH];
    int tid = threadIdx.x;
    int wid = tid >> 6, lane = tid & 63;
    int l15 = lane & 15, quad = lane >> 4;
    int rowBase = blockIdx.x * 128 + wid * 32;   // gridDim.x = 32
    int chunk = blockIdx.y;                      // gridDim.y = NCHUNK
    int col0 = chunk * COLS_PER_CHUNK;
    int part = col0 >> 12;                       // block-uniform: 0=aa, 1=p0, 2=p1
    const unsigned char* Fb = (const unsigned char*)F;

    // Staging map: 16 threads per column, 2x16B segments per thread.
    int scol = tid >> 4, sseg = tid & 15;

    // Preload A fragments: af[s][kk] covers rows rowBase+s*16.., K = kk*32
    bf16x8 af[2][8];
    #pragma unroll
    for (int s = 0; s < 2; ++s) {
        const unsigned char* ar = Fb + (size_t)(rowBase + s * 16 + l15) * 512 + quad * 16;
        #pragma unroll
        for (int kk = 0; kk < 8; ++kk)
            af[s][kk] = *(const bf16x8*)(ar + kk * 64);
    }
    // Row labels for this lane's C rows (C layout: row = quad*4 + reg)
    int rl[2][4];
    #pragma unroll
    for (int s = 0; s < 2; ++s)
        #pragma unroll
        for (int r = 0; r < 4; ++r)
            rl[s][r] = labels[rowBase + s * 16 + quad * 4 + r];

    float vmax[2][4];
    #pragma unroll
    for (int s = 0; s < 2; ++s)
        #pragma unroll
        for (int r = 0; r < 4; ++r) vmax[s][r] = NEG_INIT;

    float4 r0, r1;  // prefetch registers (one 16-col tile / block)
    auto gload = [&](int ct) {
        const unsigned char* g = Fb + (size_t)(col0 + ct * 16 + scol) * 512 + sseg * 16;
        r0 = *(const float4*)g;
        r1 = *(const float4*)(g + 256);
    };
    auto swrite = [&](int buf) {
        unsigned char* p = &lds[buf][scol * PITCH + sseg * 16];
        *(float4*)p = r0;
        *(float4*)(p + 256) = r1;
    };

    gload(0); swrite(0);
    gload(1);
    __syncthreads();

    for (int ct = 0; ct < TILES; ++ct) {
        int buf = ct & 1;
        // B fragments from LDS (2-way bank aliasing only)
        bf16x8 bfr[8];
        #pragma unroll
        for (int kk = 0; kk < 8; ++kk)
            bfr[kk] = *(const bf16x8*)&lds[buf][l15 * PITCH + quad * 16 + kk * 64];

        if (ct + 1 < TILES) swrite(buf ^ 1);   // stage next tile (regs already loaded)
        if (ct + 2 < TILES) gload(ct + 2);     // prefetch tile after next

        int c = col0 + ct * 16 + l15;
        int lc = labels[c & (NB - 1)];         // column label (shared mod NB)

        // 4 independent MFMA chains of depth 4
        f32x4 acc0a = {0.f,0.f,0.f,0.f}, acc0b = {0.f,0.f,0.f,0.f};
        f32x4 acc1a = {0.f,0.f,0.f,0.f}, acc1b = {0.f,0.f,0.f,0.f};
        #pragma unroll
        for (int kk = 0; kk < 4; ++kk) {
            acc0a = __builtin_amdgcn_mfma_f32_16x16x32_bf16(af[0][kk],   bfr[kk],   acc0a, 0, 0, 0);
            acc0b = __builtin_amdgcn_mfma_f32_16x16x32_bf16(af[0][kk+4], bfr[kk+4], acc0b, 0, 0, 0);
            acc1a = __builtin_amdgcn_mfma_f32_16x16x32_bf16(af[1][kk],   bfr[kk],   acc1a, 0, 0, 0);
            acc1b = __builtin_amdgcn_mfma_f32_16x16x32_bf16(af[1][kk+4], bfr[kk+4], acc1b, 0, 0, 0);
        }
        #pragma unroll
        for (int r = 0; r < 4; ++r) {
            float d0 = acc0a[r] + acc0b[r], d1 = acc1a[r] + acc1b[r];
            vmax[0][r] = fmaxf(vmax[0][r], (lc != rl[0][r]) ? d0 : NEG_INIT);
            vmax[1][r] = fmaxf(vmax[1][r], (lc != rl[1][r]) ? d1 : NEG_INIT);
        }
        __syncthreads();
    }

    // Reduce max across the 16 column-lanes (same quad = same rows)
    #pragma unroll
    for (int m = 1; m < 16; m <<= 1)
        #pragma unroll
        for (int s = 0; s < 2; ++s)
            #pragma unroll
            for (int r = 0; r < 4; ++r)
                vmax[s][r] = fmaxf(vmax[s][r], __shfl_xor(vmax[s][r], m, 64));

    if (l15 == 0) {
        #pragma unroll
        for (int s = 0; s < 2; ++s)
            #pragma unroll
            for (int r = 0; r < 4; ++r) {
                int row = rowBase + s * 16 + quad * 4 + r;
                partials[(size_t)part * NB * 8 + (size_t)row * 8 + (chunk & 7)] = vmax[s][r];
            }
    }
}

// Kernel 3: combine per-part chunk partials -> neg distances -> hinge -> mean.
__global__ void finalize_kernel(const float* __restrict__ partials,
                                const float* __restrict__ posArr,
                                float* __restrict__ out) {
    int row = blockIdx.x * 256 + threadIdx.x;    // grid = 16 -> 4096 rows
    const float* pa = partials + (size_t)row * 8;
    const float* pb = pa + (size_t)NB * 8;
    const float* pc = pb + (size_t)NB * 8;
    float ma = NEG_INIT, m0 = NEG_INIT, m1 = NEG_INIT;
    #pragma unroll
    for (int j = 0; j < 8; ++j) {
        ma = fmaxf(ma, pa[j]);
        m0 = fmaxf(m0, pb[j]);
        m1 = fmaxf(m1, pc[j]);
    }
    float n0 = sqrtf(fmaxf(2.0f - 2.0f * fmaxf(ma, m0), 1e-12f));
    float n1 = sqrtf(fmaxf(2.0f - 2.0f * fmaxf(ma, m1), 1e-12f));
    float l = fmaxf(posArr[row * 2 + 0] - n0 + 1.0f, 0.0f)
            + fmaxf(posArr[row * 2 + 1] - n1 + 1.0f, 0.0f);
    int lane = threadIdx.x & 63, wid = threadIdx.x >> 6;
    #pragma unroll
    for (int m = 1; m < 64; m <<= 1) l += __shfl_xor(l, m, 64);
    __shared__ float wsum[4];
    if (lane == 0) wsum[wid] = l;
    __syncthreads();
    if (threadIdx.x == 0) {
        float s = wsum[0] + wsum[1] + wsum[2] + wsum[3];
        atomicAdd(out, s * (1.0f / (NB * NP)));
    }
}

extern "C" void kernel_launch(void* const* d_in, const int* in_sizes, int n_in,
                              void* d_out, int out_size, void* d_ws, size_t ws_size,
                              hipStream_t stream) {
    const float* anchor   = (const float*)d_in[0];
    const float* positive = (const float*)d_in[1];
    const int*   labels   = (const int*)d_in[2];
    float* out = (float*)d_out;

    unsigned short* F = (unsigned short*)((char*)d_ws + WS_F_OFF);
    float* posArr     = (float*)((char*)d_ws + WS_POS_OFF);
    float* partials   = (float*)((char*)d_ws + WS_PART_OFF);

    norm_pos_kernel<<<TOT / 4, 256, 0, stream>>>(anchor, positive, F, posArr);
    gram_max_kernel<<<dim3(NB / 128, NCHUNK), 256, 0, stream>>>(F, labels, partials);
    hipMemsetAsync(d_out, 0, sizeof(float), stream);
    finalize_kernel<<<NB / 256, 256, 0, stream>>>(partials, posArr, out);
}